// Round 2
// 1564.905 us; speedup vs baseline: 1.0004x; 1.0004x over previous
//
#include <hip/hip_runtime.h>

typedef unsigned short ushort_t;
typedef unsigned int uint_t;
typedef __attribute__((ext_vector_type(8))) short short8;
typedef __attribute__((ext_vector_type(4))) short s16x4;
typedef __attribute__((ext_vector_type(4))) float f32x4;

#define LDS_AS __attribute__((address_space(3)))
#define GLB_AS __attribute__((address_space(1)))

__device__ __forceinline__ float bf2f(ushort_t h) {
    uint_t u = ((uint_t)h) << 16;
    return __builtin_bit_cast(float, u);
}
__device__ __forceinline__ ushort_t f2bf(float f) {
    uint_t u = __builtin_bit_cast(uint_t, f);
    u += 0x7fffu + ((u >> 16) & 1u);
    return (ushort_t)(u >> 16);
}

// ---------------------------------------------------------------------------
// fp32 -> bf16 convert, 8 elements/thread, vectorized.
// ---------------------------------------------------------------------------
__global__ __launch_bounds__(256) void cvt_kernel(const float* __restrict__ src,
                                                  ushort_t* __restrict__ dst) {
    size_t i = ((size_t)blockIdx.x * 256 + threadIdx.x) * 8;
    f32x4 a = *(const f32x4*)(src + i);
    f32x4 b = *(const f32x4*)(src + i + 4);
    short8 o;
#pragma unroll
    for (int j = 0; j < 4; ++j) o[j] = (short)f2bf(a[j]);
#pragma unroll
    for (int j = 0; j < 4; ++j) o[4 + j] = (short)f2bf(b[j]);
    *(short8*)(dst + i) = o;
}

// ---------------------------------------------------------------------------
// GEMM: C[M,N] = A[M,K] * W[N,K]^T, bf16 in, fp32 accum, bf16 or f32 out.
// 128x128 block tile, BK=32, 4 waves (2x2), each wave 64x64 = 4x4 MFMA tiles.
// global_load_lds width=16 staging (m97 structure).
// ---------------------------------------------------------------------------
template <bool OUT_F32>
__global__ __launch_bounds__(256) void gemm_bt(const ushort_t* __restrict__ A,
                                               const ushort_t* __restrict__ W,
                                               void* __restrict__ Cv,
                                               int M, int N, int K) {
    __shared__ ushort_t As[128 * 32];
    __shared__ ushort_t Bs[128 * 32];
    const int tid = threadIdx.x;
    const int lane = tid & 63;
    const int w = tid >> 6;
    const int wr = (w >> 1) * 64;
    const int wc = (w & 1) * 64;
    const int row0 = blockIdx.y * 128;
    const int col0 = blockIdx.x * 128;
    const int l15 = lane & 15;
    const int l4 = lane >> 4;

    f32x4 acc[4][4];
#pragma unroll
    for (int i = 0; i < 4; ++i)
#pragma unroll
        for (int j = 0; j < 4; ++j) acc[i][j] = (f32x4)0.0f;

    for (int k0 = 0; k0 < K; k0 += 32) {
        __syncthreads();
#pragma unroll
        for (int i = 0; i < 2; ++i) {
            int c = i * 256 + tid;
            int r = c >> 2;
            int cc = (c & 3) * 8;
            __builtin_amdgcn_global_load_lds(
                (const GLB_AS void*)(A + (size_t)(row0 + r) * K + k0 + cc),
                (LDS_AS void*)(&As[c * 8]), 16, 0, 0);
            __builtin_amdgcn_global_load_lds(
                (const GLB_AS void*)(W + (size_t)(col0 + r) * K + k0 + cc),
                (LDS_AS void*)(&Bs[c * 8]), 16, 0, 0);
        }
        __syncthreads();

        short8 aF[4], bF[4];
#pragma unroll
        for (int mt = 0; mt < 4; ++mt)
            aF[mt] = *(const short8*)&As[(wr + mt * 16 + l15) * 32 + l4 * 8];
#pragma unroll
        for (int nt = 0; nt < 4; ++nt)
            bF[nt] = *(const short8*)&Bs[(wc + nt * 16 + l15) * 32 + l4 * 8];
#pragma unroll
        for (int mt = 0; mt < 4; ++mt)
#pragma unroll
            for (int nt = 0; nt < 4; ++nt)
                acc[mt][nt] = __builtin_amdgcn_mfma_f32_16x16x32_bf16(
                    aF[mt], bF[nt], acc[mt][nt], 0, 0, 0);
    }

    // C/D layout: col = lane&15, row = (lane>>4)*4 + reg
#pragma unroll
    for (int mt = 0; mt < 4; ++mt)
#pragma unroll
        for (int nt = 0; nt < 4; ++nt)
#pragma unroll
            for (int r = 0; r < 4; ++r) {
                int row = row0 + wr + mt * 16 + l4 * 4 + r;
                int col = col0 + wc + nt * 16 + l15;
                if (OUT_F32)
                    ((float*)Cv)[(size_t)row * N + col] = acc[mt][nt][r];
                else
                    ((ushort_t*)Cv)[(size_t)row * N + col] = f2bf(acc[mt][nt][r]);
            }
}

// ---------------------------------------------------------------------------
// RoPE (in-place, bf16). ang = s * 10000^(-j/64), s = row % 2048.
// ---------------------------------------------------------------------------
__global__ __launch_bounds__(256) void rope_kernel(ushort_t* __restrict__ X,
                                                   int lognh) {
    int idx = blockIdx.x * 256 + threadIdx.x;
    int j = idx & 63;
    int t = idx >> 6;
    int h = t & ((1 << lognh) - 1);
    int r = t >> lognh;
    int s = r & 2047;
    int stride = 128 << lognh;
    size_t ofs = (size_t)r * stride + h * 128 + j;
    float inv = exp2f(-0.20762050593046014f * (float)j);
    float ang = (float)s * inv;
    float c = cosf(ang);
    float sn = sinf(ang);
    float x1 = bf2f(X[ofs]);
    float x2 = bf2f(X[ofs + 64]);
    X[ofs] = f2bf(x1 * c - x2 * sn);
    X[ofs + 64] = f2bf(x2 * c + x1 * sn);
}

// ---------------------------------------------------------------------------
// MFMA flash attention (causal, GQA 4:1).
// Block = (b, h, 64-query tile); 4 waves x 16 q-rows. BK=64 keys/iter.
// (Retry of round-1 kernel — previous bench died to container infra, no data.)
//  - launch_bounds(256,4): 4 blocks/CU (LDS cut to 27.6KB via bf16 P buffer)
//  - heavy-first qt remap: 32-iter causal tiles dispatch first (balance)
//  - T14: V tile prefetched to regs; raw s_barrier (no vmcnt drain) so the
//    prefetch stays in flight across barriers; LDS write from regs after B1
//  - T13: defer-rescale (skip alpha/exp/O-rescale when __any(rm-m <= 8))
//  - T5: s_setprio(1) around MFMA clusters
//  - P stored bf16 in LDS (halves traffic, direct short8 A-frag read in PV)
// MFMA layouts (verified): A/B lane holds [m|n = lane&15][k=(lane>>4)*8+j];
// C/D col=lane&15, row=(lane>>4)*4+reg.
// ---------------------------------------------------------------------------
__global__ __launch_bounds__(256, 4) void attn_kernel(const ushort_t* __restrict__ Q,
                                                      const ushort_t* __restrict__ K,
                                                      const ushort_t* __restrict__ V,
                                                      ushort_t* __restrict__ Cx) {
    __shared__ ushort_t Vt[128 * 72];   // V^T: Vt[d][key], stride 72 (18432 B)
    __shared__ ushort_t Psb[64 * 72];   // P bf16: Psb[q][key], stride 72 (9216 B)

    const int tid = threadIdx.x;
    const int l = tid & 63;
    const int w = tid >> 6;
    const int l15 = l & 15;
    const int l4 = l >> 4;

    const int blk = blockIdx.x;
    const int qt = 31 - (blk & 31);   // heavy-first: longest causal tiles launch first
    const int h = (blk >> 5) & 31;
    const int b = blk >> 10;
    const int kvh = h >> 2;

    const size_t qrow0 = (size_t)(b * 2048 + qt * 64 + w * 16);

    // ---- Q fragments: 16 q-rows x 128 d, once per block ----
    short8 qf[4];
    {
        const ushort_t* qp = Q + (qrow0 + l15) * 4096 + h * 128 + l4 * 8;
#pragma unroll
        for (int kt = 0; kt < 4; ++kt) qf[kt] = *(const short8*)(qp + kt * 32);
    }

    f32x4 O[8];
#pragma unroll
    for (int dt = 0; dt < 8; ++dt) O[dt] = (f32x4)0.0f;
    float m_i[4], l_i[4];
#pragma unroll
    for (int r = 0; r < 4; ++r) { m_i[r] = -1.0e30f; l_i[r] = 0.0f; }

    const float scale = 0.08838834764831845f;  // 128^-0.5

    // V staging assignment: thread -> 4 adjacent keys x 8 adjacent d
    const int sk0 = (tid & 15) * 4;
    const int sd0 = (tid >> 4) * 8;
    const ushort_t* vb0 = V + (size_t)(b * 2048 + sk0) * 1024 + kvh * 128 + sd0;

    // ---- prefetch V tile 0 into registers (T14) ----
    short8 vr[4];
#pragma unroll
    for (int i = 0; i < 4; ++i) vr[i] = *(const short8*)(vb0 + (size_t)i * 1024);

    for (int kti = 0; kti <= qt; ++kti) {
        // B1: Vt free for overwrite. Raw barrier: each wave's prior PV ds_reads
        // completed by data-dependence before its MFMAs issued; no vmcnt drain,
        // so the V prefetch (and nothing else) stays in flight.
        __builtin_amdgcn_s_barrier();

        // ---- write Vt transposed from prefetched regs ----
#pragma unroll
        for (int j = 0; j < 8; ++j) {
            s16x4 pk;
            pk[0] = vr[0][j]; pk[1] = vr[1][j];
            pk[2] = vr[2][j]; pk[3] = vr[3][j];
            *(s16x4*)&Vt[(sd0 + j) * 72 + sk0] = pk;
        }
        // ---- issue next V-tile prefetch; latency hides under QK+softmax+PV ----
        if (kti < qt) {
            const ushort_t* vp = vb0 + (size_t)(kti + 1) * 64 * 1024;
#pragma unroll
            for (int i = 0; i < 4; ++i) vr[i] = *(const short8*)(vp + (size_t)i * 1024);
        }

        // ---- QK^T: S[16q x 64k] per wave ----
        const ushort_t* kbase = K + (size_t)(b * 2048 + kti * 64) * 1024 + kvh * 128;
        f32x4 S[4];
        __builtin_amdgcn_s_setprio(1);
#pragma unroll
        for (int ct = 0; ct < 4; ++ct) {
            S[ct] = (f32x4)0.0f;
            const ushort_t* kp = kbase + (size_t)(ct * 16 + l15) * 1024 + l4 * 8;
#pragma unroll
            for (int kt = 0; kt < 4; ++kt) {
                short8 kf = *(const short8*)(kp + kt * 32);
                S[ct] = __builtin_amdgcn_mfma_f32_16x16x32_bf16(qf[kt], kf, S[ct], 0, 0, 0);
            }
        }
        __builtin_amdgcn_s_setprio(0);

        // ---- online softmax (per C-layout row r: q = w*16 + l4*4 + r) ----
        const int diag = (kti == qt);
#pragma unroll
        for (int r = 0; r < 4; ++r) {
            int qy = w * 16 + l4 * 4 + r;
            float sv[4];
#pragma unroll
            for (int ct = 0; ct < 4; ++ct) {
                float x = S[ct][r] * scale;
                if (diag && (ct * 16 + l15) > qy) x = -1.0e30f;
                sv[ct] = x;
            }
            float rm = fmaxf(fmaxf(sv[0], sv[1]), fmaxf(sv[2], sv[3]));
#pragma unroll
            for (int d = 1; d <= 8; d <<= 1) rm = fmaxf(rm, __shfl_xor(rm, d, 64));
            // T13: defer rescale while max growth <= 8 (p bounded by e^8; bf16-safe)
            if (__any(rm - m_i[r] > 8.0f)) {
                float nm = fmaxf(m_i[r], rm);
                float al = __expf(m_i[r] - nm);
                m_i[r] = nm;
                l_i[r] *= al;
#pragma unroll
                for (int dt = 0; dt < 8; ++dt) O[dt][r] *= al;
            }
            float rs = 0.0f;
#pragma unroll
            for (int ct = 0; ct < 4; ++ct) {
                float p = __expf(sv[ct] - m_i[r]);
                Psb[(size_t)qy * 72 + ct * 16 + l15] = f2bf(p);
                rs += p;
            }
#pragma unroll
            for (int d = 1; d <= 8; d <<= 1) rs += __shfl_xor(rs, d, 64);
            l_i[r] += rs;
        }

        // B2: drain LDS writes only (lgkmcnt), NOT vmcnt -> V prefetch stays live.
        asm volatile("s_waitcnt lgkmcnt(0)" ::: "memory");
        __builtin_amdgcn_s_barrier();

        // ---- O += P * V  (A = P bf16 from Psb, B = Vt) ----
        __builtin_amdgcn_s_setprio(1);
#pragma unroll
        for (int kpt = 0; kpt < 2; ++kpt) {
            short8 pf = *(const short8*)&Psb[(size_t)(w * 16 + l15) * 72 + kpt * 32 + l4 * 8];
#pragma unroll
            for (int dt = 0; dt < 8; ++dt) {
                short8 vf = *(const short8*)&Vt[(size_t)(dt * 16 + l15) * 72 + kpt * 32 + l4 * 8];
                O[dt] = __builtin_amdgcn_mfma_f32_16x16x32_bf16(pf, vf, O[dt], 0, 0, 0);
            }
        }
        __builtin_amdgcn_s_setprio(0);
    }

    // ---- epilogue: O /= l, write ctx (bf16) ----
    float rl[4];
#pragma unroll
    for (int r = 0; r < 4; ++r) rl[r] = 1.0f / l_i[r];
#pragma unroll
    for (int dt = 0; dt < 8; ++dt)
#pragma unroll
        for (int r = 0; r < 4; ++r) {
            size_t gofs = (qrow0 + l4 * 4 + r) * 4096 + h * 128 + dt * 16 + l15;
            Cx[gofs] = f2bf(O[dt][r] * rl[r]);
        }
}

// ---------------------------------------------------------------------------
extern "C" void kernel_launch(void* const* d_in, const int* in_sizes, int n_in,
                              void* d_out, int out_size, void* d_ws, size_t ws_size,
                              hipStream_t stream) {
    const float* q  = (const float*)d_in[0];
    const float* k  = (const float*)d_in[1];
    const float* v  = (const float*)d_in[2];
    const float* Wq = (const float*)d_in[3];
    const float* Wk = (const float*)d_in[4];
    const float* Wv = (const float*)d_in[5];
    const float* Wd = (const float*)d_in[6];
    float* out = (float*)d_out;

    char* ws = (char*)d_ws;
    ushort_t* Abf = (ushort_t*)(ws);                       // 32MB (activation bf16)
    ushort_t* Wbf = (ushort_t*)(ws + (size_t)33554432);    // 32MB (weight bf16)
    ushort_t* Qb  = (ushort_t*)(ws + (size_t)67108864);    // 4096x4096 bf16 = 32MB
    ushort_t* Kb  = (ushort_t*)(ws + (size_t)100663296);   // 4096x1024 bf16 =  8MB
    ushort_t* Vb  = (ushort_t*)(ws + (size_t)109051904);   // 4096x1024 bf16 =  8MB
    ushort_t* Cx  = (ushort_t*)(ws + (size_t)117440512);   // 4096x4096 bf16 = 32MB

    dim3 blk(256);
    // Q projection
    hipLaunchKernelGGL(cvt_kernel, dim3(8192), blk, 0, stream, q, Abf);
    hipLaunchKernelGGL(cvt_kernel, dim3(8192), blk, 0, stream, Wq, Wbf);
    hipLaunchKernelGGL((gemm_bt<false>), dim3(32, 32), blk, 0, stream, Abf, Wbf, (void*)Qb, 4096, 4096, 4096);
    // K projection
    hipLaunchKernelGGL(cvt_kernel, dim3(8192), blk, 0, stream, k, Abf);
    hipLaunchKernelGGL(cvt_kernel, dim3(2048), blk, 0, stream, Wk, Wbf);
    hipLaunchKernelGGL((gemm_bt<false>), dim3(8, 32), blk, 0, stream, Abf, Wbf, (void*)Kb, 4096, 1024, 4096);
    // V projection
    hipLaunchKernelGGL(cvt_kernel, dim3(8192), blk, 0, stream, v, Abf);
    hipLaunchKernelGGL(cvt_kernel, dim3(2048), blk, 0, stream, Wv, Wbf);
    hipLaunchKernelGGL((gemm_bt<false>), dim3(8, 32), blk, 0, stream, Abf, Wbf, (void*)Vb, 4096, 1024, 4096);
    // RoPE
    hipLaunchKernelGGL(rope_kernel, dim3(32768), blk, 0, stream, Qb, 5);  // 32 heads
    hipLaunchKernelGGL(rope_kernel, dim3(8192),  blk, 0, stream, Kb, 3);  //  8 heads
    // Attention (MFMA)
    hipLaunchKernelGGL(attn_kernel, dim3(2048), blk, 0, stream, Qb, Kb, Vb, Cx);
    // Output projection (fp32 out)
    hipLaunchKernelGGL(cvt_kernel, dim3(8192), blk, 0, stream, Wd, Wbf);
    hipLaunchKernelGGL((gemm_bt<true>), dim3(32, 32), blk, 0, stream, Cx, Wbf, (void*)out, 4096, 4096, 4096);
}

// Round 3
// 1234.795 us; speedup vs baseline: 1.2678x; 1.2673x over previous
//
#include <hip/hip_runtime.h>

typedef unsigned short ushort_t;
typedef unsigned int uint_t;
typedef __attribute__((ext_vector_type(8))) short short8;
typedef __attribute__((ext_vector_type(4))) short s16x4;
typedef __attribute__((ext_vector_type(4))) float f32x4;

#define LDS_AS __attribute__((address_space(3)))
#define GLB_AS __attribute__((address_space(1)))

__device__ __forceinline__ float bf2f(ushort_t h) {
    uint_t u = ((uint_t)h) << 16;
    return __builtin_bit_cast(float, u);
}
__device__ __forceinline__ ushort_t f2bf(float f) {
    uint_t u = __builtin_bit_cast(uint_t, f);
    u += 0x7fffu + ((u >> 16) & 1u);
    return (ushort_t)(u >> 16);
}

// ---------------------------------------------------------------------------
// fp32 -> bf16 convert, 8 elements/thread, vectorized.
// ---------------------------------------------------------------------------
__global__ __launch_bounds__(256) void cvt_kernel(const float* __restrict__ src,
                                                  ushort_t* __restrict__ dst) {
    size_t i = ((size_t)blockIdx.x * 256 + threadIdx.x) * 8;
    f32x4 a = *(const f32x4*)(src + i);
    f32x4 b = *(const f32x4*)(src + i + 4);
    short8 o;
#pragma unroll
    for (int j = 0; j < 4; ++j) o[j] = (short)f2bf(a[j]);
#pragma unroll
    for (int j = 0; j < 4; ++j) o[4 + j] = (short)f2bf(b[j]);
    *(short8*)(dst + i) = o;
}

// ---------------------------------------------------------------------------
// GEMM: C[M,N] = A[M,K] * W[N,K]^T, bf16 in, fp32 accum, bf16 or f32 out.
// 128x128 block tile, BK=32, 4 waves (2x2), each wave 64x64 = 4x4 MFMA tiles.
// global_load_lds width=16 staging (m97 structure). (unchanged this round)
// ---------------------------------------------------------------------------
template <bool OUT_F32>
__global__ __launch_bounds__(256) void gemm_bt(const ushort_t* __restrict__ A,
                                               const ushort_t* __restrict__ W,
                                               void* __restrict__ Cv,
                                               int M, int N, int K) {
    __shared__ ushort_t As[128 * 32];
    __shared__ ushort_t Bs[128 * 32];
    const int tid = threadIdx.x;
    const int lane = tid & 63;
    const int w = tid >> 6;
    const int wr = (w >> 1) * 64;
    const int wc = (w & 1) * 64;
    const int row0 = blockIdx.y * 128;
    const int col0 = blockIdx.x * 128;
    const int l15 = lane & 15;
    const int l4 = lane >> 4;

    f32x4 acc[4][4];
#pragma unroll
    for (int i = 0; i < 4; ++i)
#pragma unroll
        for (int j = 0; j < 4; ++j) acc[i][j] = (f32x4)0.0f;

    for (int k0 = 0; k0 < K; k0 += 32) {
        __syncthreads();
#pragma unroll
        for (int i = 0; i < 2; ++i) {
            int c = i * 256 + tid;
            int r = c >> 2;
            int cc = (c & 3) * 8;
            __builtin_amdgcn_global_load_lds(
                (const GLB_AS void*)(A + (size_t)(row0 + r) * K + k0 + cc),
                (LDS_AS void*)(&As[c * 8]), 16, 0, 0);
            __builtin_amdgcn_global_load_lds(
                (const GLB_AS void*)(W + (size_t)(col0 + r) * K + k0 + cc),
                (LDS_AS void*)(&Bs[c * 8]), 16, 0, 0);
        }
        __syncthreads();

        short8 aF[4], bF[4];
#pragma unroll
        for (int mt = 0; mt < 4; ++mt)
            aF[mt] = *(const short8*)&As[(wr + mt * 16 + l15) * 32 + l4 * 8];
#pragma unroll
        for (int nt = 0; nt < 4; ++nt)
            bF[nt] = *(const short8*)&Bs[(wc + nt * 16 + l15) * 32 + l4 * 8];
#pragma unroll
        for (int mt = 0; mt < 4; ++mt)
#pragma unroll
            for (int nt = 0; nt < 4; ++nt)
                acc[mt][nt] = __builtin_amdgcn_mfma_f32_16x16x32_bf16(
                    aF[mt], bF[nt], acc[mt][nt], 0, 0, 0);
    }

    // C/D layout: col = lane&15, row = (lane>>4)*4 + reg
#pragma unroll
    for (int mt = 0; mt < 4; ++mt)
#pragma unroll
        for (int nt = 0; nt < 4; ++nt)
#pragma unroll
            for (int r = 0; r < 4; ++r) {
                int row = row0 + wr + mt * 16 + l4 * 4 + r;
                int col = col0 + wc + nt * 16 + l15;
                if (OUT_F32)
                    ((float*)Cv)[(size_t)row * N + col] = acc[mt][nt][r];
                else
                    ((ushort_t*)Cv)[(size_t)row * N + col] = f2bf(acc[mt][nt][r]);
            }
}

// ---------------------------------------------------------------------------
// RoPE (in-place, bf16). ang = s * 10000^(-j/64), s = row % 2048.
// ---------------------------------------------------------------------------
__global__ __launch_bounds__(256) void rope_kernel(ushort_t* __restrict__ X,
                                                   int lognh) {
    int idx = blockIdx.x * 256 + threadIdx.x;
    int j = idx & 63;
    int t = idx >> 6;
    int h = t & ((1 << lognh) - 1);
    int r = t >> lognh;
    int s = r & 2047;
    int stride = 128 << lognh;
    size_t ofs = (size_t)r * stride + h * 128 + j;
    float inv = exp2f(-0.20762050593046014f * (float)j);
    float ang = (float)s * inv;
    float c = cosf(ang);
    float sn = sinf(ang);
    float x1 = bf2f(X[ofs]);
    float x2 = bf2f(X[ofs + 64]);
    X[ofs] = f2bf(x1 * c - x2 * sn);
    X[ofs + 64] = f2bf(x2 * c + x1 * sn);
}

// ---------------------------------------------------------------------------
// MFMA flash attention (causal, GQA 4:1) — round 3 restructure.
// Post-mortem r2: occupancy fix was a no-op (LDS already allowed 4 blk/CU);
// implied per-iteration wall ~12-25k cyc vs ~3-4k issue cost -> serial
// cross-lane softmax (32 ds_bpermute/iter in 4-deep chains) + load imbalance
// (1..32 iters/block, 2048 blocks) are the theory this round.
// Changes:
//  - SWAPPED QK^T: S^T = mfma(K_frag, Q_frag). Identical frag layouts for
//    A/B mean the same loads work; output now has q = lane&15, so the row
//    max/sum is an IN-LANE 16-value tree + 2 shfl_xor (16/32) instead of
//    32 bpermutes. m_i/l_i become per-lane scalars.
//  - PAIRED Q-TILES {p, 31-p}: every block = exactly 33 iterations.
//    Grid 1024 = 256 CU x 4 blocks, all resident, no backfill/tail.
//  - Packed P writes: 4x ds_write_b64 instead of 16x ds_write_b16.
//  - Kept: T14 V reg-prefetch + raw barriers, T13 defer-rescale, T5 setprio.
// MFMA layouts (verified via gemm_bt): A/B frag lane holds [idx = lane&15]
// [k=(lane>>4)*8+j]; C/D col(n)=lane&15, row(m)=(lane>>4)*4+reg.
// ---------------------------------------------------------------------------
__global__ __launch_bounds__(256, 4) void attn_kernel(const ushort_t* __restrict__ Q,
                                                      const ushort_t* __restrict__ K,
                                                      const ushort_t* __restrict__ V,
                                                      ushort_t* __restrict__ Cx) {
    __shared__ ushort_t Vt[128 * 72];   // V^T: Vt[d][key], stride 72 (18432 B)
    __shared__ ushort_t Psb[64 * 72];   // P bf16: Psb[q][key], stride 72 (9216 B)

    const int tid = threadIdx.x;
    const int l = tid & 63;
    const int w = tid >> 6;
    const int l15 = l & 15;
    const int l4 = l >> 4;

    const int blk = blockIdx.x;         // 1024 blocks: pair(16) x h(32) x b(2)
    const int pr = blk & 15;
    const int h = (blk >> 4) & 31;
    const int b = blk >> 9;
    const int kvh = h >> 2;

    const float scale = 0.08838834764831845f;  // 128^-0.5

    // V staging assignment: thread -> 4 adjacent keys x 8 adjacent d
    const int sk0 = (tid & 15) * 4;
    const int sd0 = (tid >> 4) * 8;
    const ushort_t* vb0 = V + (size_t)(b * 2048 + sk0) * 1024 + kvh * 128 + sd0;
    const ushort_t* kb0 = K + (size_t)(b * 2048) * 1024 + kvh * 128;

#pragma unroll 1
    for (int half = 0; half < 2; ++half) {
        const int qt = half ? (31 - pr) : pr;
        const size_t qrow0 = (size_t)(b * 2048 + qt * 64 + w * 16);

        // ---- Q fragments: 16 q-rows x 128 d ----
        short8 qf[4];
        {
            const ushort_t* qp = Q + (qrow0 + l15) * 4096 + h * 128 + l4 * 8;
#pragma unroll
            for (int kt = 0; kt < 4; ++kt) qf[kt] = *(const short8*)(qp + kt * 32);
        }

        f32x4 O[8];
#pragma unroll
        for (int dt = 0; dt < 8; ++dt) O[dt] = (f32x4)0.0f;
        float m_i = -1.0e30f, l_i = 0.0f;

        // ---- prefetch V tile 0 into registers (T14) ----
        short8 vr[4];
#pragma unroll
        for (int i = 0; i < 4; ++i) vr[i] = *(const short8*)(vb0 + (size_t)i * 1024);

#pragma unroll 1
        for (int kti = 0; kti <= qt; ++kti) {
            // B1: Vt free for overwrite (prev PV ds_reads done by data-dep).
            // Raw barrier: no vmcnt drain, V prefetch stays in flight.
            __builtin_amdgcn_s_barrier();

            // ---- write Vt transposed from prefetched regs ----
#pragma unroll
            for (int j = 0; j < 8; ++j) {
                s16x4 pk;
                pk[0] = vr[0][j]; pk[1] = vr[1][j];
                pk[2] = vr[2][j]; pk[3] = vr[3][j];
                *(s16x4*)&Vt[(sd0 + j) * 72 + sk0] = pk;
            }
            // ---- issue next V-tile prefetch (hides under QK+softmax+PV) ----
            if (kti < qt) {
                const ushort_t* vp = vb0 + (size_t)(kti + 1) * 64 * 1024;
#pragma unroll
                for (int i = 0; i < 4; ++i) vr[i] = *(const short8*)(vp + (size_t)i * 1024);
            }

            // ---- QK^T swapped: St[key][q] per wave (A=K, B=Q) ----
            const ushort_t* kbase = kb0 + (size_t)(kti * 64) * 1024;
            f32x4 S[4];
            __builtin_amdgcn_s_setprio(1);
#pragma unroll
            for (int ct = 0; ct < 4; ++ct) {
                S[ct] = (f32x4)0.0f;
                const ushort_t* kp = kbase + (size_t)(ct * 16 + l15) * 1024 + l4 * 8;
#pragma unroll
                for (int kt = 0; kt < 4; ++kt) {
                    short8 kf = *(const short8*)(kp + kt * 32);
                    S[ct] = __builtin_amdgcn_mfma_f32_16x16x32_bf16(kf, qf[kt], S[ct], 0, 0, 0);
                }
            }
            __builtin_amdgcn_s_setprio(0);

            // ---- in-register online softmax ----
            // Lane holds 16 scores for q-row (w*16 + l15):
            //   key = ct*16 + l4*4 + r  in S[ct][r].
            const int diag = (kti == qt);
            const int qlq = w * 16 + l15;   // tile-local q row
            float sv[4][4];
#pragma unroll
            for (int ct = 0; ct < 4; ++ct)
#pragma unroll
                for (int r = 0; r < 4; ++r) {
                    float x = S[ct][r] * scale;
                    if (diag && (ct * 16 + l4 * 4 + r) > qlq) x = -1.0e30f;
                    sv[ct][r] = x;
                }
            // in-lane max of 16, then reduce across the 4 l4-groups
            float rm = sv[0][0];
#pragma unroll
            for (int ct = 0; ct < 4; ++ct)
#pragma unroll
                for (int r = 0; r < 4; ++r) rm = fmaxf(rm, sv[ct][r]);
            rm = fmaxf(rm, __shfl_xor(rm, 16, 64));
            rm = fmaxf(rm, __shfl_xor(rm, 32, 64));
            // T13: defer rescale while max growth <= 8 (p bounded by e^8)
            if (__any(rm - m_i > 8.0f)) {
                float nm = fmaxf(m_i, rm);
                float al = __expf(m_i - nm);
                m_i = nm;
                l_i *= al;
                float alr[4];
#pragma unroll
                for (int r = 0; r < 4; ++r) alr[r] = __shfl(al, l4 * 4 + r, 16);
#pragma unroll
                for (int dt = 0; dt < 8; ++dt)
#pragma unroll
                    for (int r = 0; r < 4; ++r) O[dt][r] *= alr[r];
            }
            // exp + packed bf16 store to Psb[q][key] (keys ct*16+4*l4+0..3)
            float rs = 0.0f;
#pragma unroll
            for (int ct = 0; ct < 4; ++ct) {
                s16x4 pk;
#pragma unroll
                for (int r = 0; r < 4; ++r) {
                    float p = __expf(sv[ct][r] - m_i);
                    rs += p;
                    pk[r] = (short)f2bf(p);
                }
                *(s16x4*)&Psb[(size_t)(w * 16 + l15) * 72 + ct * 16 + l4 * 4] = pk;
            }
            rs += __shfl_xor(rs, 16, 64);
            rs += __shfl_xor(rs, 32, 64);
            l_i += rs;

            // B2: drain LDS writes only (lgkmcnt), NOT vmcnt.
            asm volatile("s_waitcnt lgkmcnt(0)" ::: "memory");
            __builtin_amdgcn_s_barrier();

            // ---- O += P * V  (A = P bf16 from Psb, B = Vt) ----
            __builtin_amdgcn_s_setprio(1);
#pragma unroll
            for (int kpt = 0; kpt < 2; ++kpt) {
                short8 pf = *(const short8*)&Psb[(size_t)(w * 16 + l15) * 72 + kpt * 32 + l4 * 8];
#pragma unroll
                for (int dt = 0; dt < 8; ++dt) {
                    short8 vf = *(const short8*)&Vt[(size_t)(dt * 16 + l15) * 72 + kpt * 32 + l4 * 8];
                    O[dt] = __builtin_amdgcn_mfma_f32_16x16x32_bf16(pf, vf, O[dt], 0, 0, 0);
                }
            }
            __builtin_amdgcn_s_setprio(0);
        }

        // ---- epilogue: O /= l (l_i fetched from the lane holding that row) ----
        float rlr[4];
#pragma unroll
        for (int r = 0; r < 4; ++r) rlr[r] = 1.0f / __shfl(l_i, l4 * 4 + r, 16);
#pragma unroll
        for (int dt = 0; dt < 8; ++dt)
#pragma unroll
            for (int r = 0; r < 4; ++r) {
                size_t gofs = (qrow0 + l4 * 4 + r) * 4096 + h * 128 + dt * 16 + l15;
                Cx[gofs] = f2bf(O[dt][r] * rlr[r]);
            }
    }
}

// ---------------------------------------------------------------------------
extern "C" void kernel_launch(void* const* d_in, const int* in_sizes, int n_in,
                              void* d_out, int out_size, void* d_ws, size_t ws_size,
                              hipStream_t stream) {
    const float* q  = (const float*)d_in[0];
    const float* k  = (const float*)d_in[1];
    const float* v  = (const float*)d_in[2];
    const float* Wq = (const float*)d_in[3];
    const float* Wk = (const float*)d_in[4];
    const float* Wv = (const float*)d_in[5];
    const float* Wd = (const float*)d_in[6];
    float* out = (float*)d_out;

    char* ws = (char*)d_ws;
    ushort_t* Abf = (ushort_t*)(ws);                       // 32MB (activation bf16)
    ushort_t* Wbf = (ushort_t*)(ws + (size_t)33554432);    // 32MB (weight bf16)
    ushort_t* Qb  = (ushort_t*)(ws + (size_t)67108864);    // 4096x4096 bf16 = 32MB
    ushort_t* Kb  = (ushort_t*)(ws + (size_t)100663296);   // 4096x1024 bf16 =  8MB
    ushort_t* Vb  = (ushort_t*)(ws + (size_t)109051904);   // 4096x1024 bf16 =  8MB
    ushort_t* Cx  = (ushort_t*)(ws + (size_t)117440512);   // 4096x4096 bf16 = 32MB

    dim3 blk(256);
    // Q projection
    hipLaunchKernelGGL(cvt_kernel, dim3(8192), blk, 0, stream, q, Abf);
    hipLaunchKernelGGL(cvt_kernel, dim3(8192), blk, 0, stream, Wq, Wbf);
    hipLaunchKernelGGL((gemm_bt<false>), dim3(32, 32), blk, 0, stream, Abf, Wbf, (void*)Qb, 4096, 4096, 4096);
    // K projection
    hipLaunchKernelGGL(cvt_kernel, dim3(8192), blk, 0, stream, k, Abf);
    hipLaunchKernelGGL(cvt_kernel, dim3(2048), blk, 0, stream, Wk, Wbf);
    hipLaunchKernelGGL((gemm_bt<false>), dim3(8, 32), blk, 0, stream, Abf, Wbf, (void*)Kb, 4096, 1024, 4096);
    // V projection
    hipLaunchKernelGGL(cvt_kernel, dim3(8192), blk, 0, stream, v, Abf);
    hipLaunchKernelGGL(cvt_kernel, dim3(2048), blk, 0, stream, Wv, Wbf);
    hipLaunchKernelGGL((gemm_bt<false>), dim3(8, 32), blk, 0, stream, Abf, Wbf, (void*)Vb, 4096, 1024, 4096);
    // RoPE
    hipLaunchKernelGGL(rope_kernel, dim3(32768), blk, 0, stream, Qb, 5);  // 32 heads
    hipLaunchKernelGGL(rope_kernel, dim3(8192),  blk, 0, stream, Kb, 3);  //  8 heads
    // Attention (MFMA) — 1024 uniform-work blocks (16 pairs x 32 h x 2 b)
    hipLaunchKernelGGL(attn_kernel, dim3(1024), blk, 0, stream, Qb, Kb, Vb, Cx);
    // Output projection (fp32 out)
    hipLaunchKernelGGL(cvt_kernel, dim3(8192), blk, 0, stream, Wd, Wbf);
    hipLaunchKernelGGL((gemm_bt<true>), dim3(32, 32), blk, 0, stream, Cx, Wbf, (void*)out, 4096, 4096, 4096);
}